// Round 1
// baseline (70.136 us; speedup 1.0000x reference)
//
#include <hip/hip_runtime.h>

#define NQ   10
#define DIM  1024
#define NP   57                       // 6*NQ - 3
#define WMUL 0.6324555320336759f      // sqrt(2/5)

__global__ __launch_bounds__(256) void qupool_sv_kernel(
    const float* __restrict__ xr,
    const float* __restrict__ xi,
    const float* __restrict__ w,
    const int*   __restrict__ dimA_p,
    float* __restrict__ out,
    int out_size)
{
    __shared__ float sre[DIM];
    __shared__ float sim[DIM];
    __shared__ float sc[NP], ss[NP];

    const int b = blockIdx.x;
    const int t = threadIdx.x;

    // --- gate parameters: cos/sin of (w * WMUL / 2) ---
    if (t < NP) {
        float th = w[t] * (WMUL * 0.5f);
        sc[t] = cosf(th);
        ss[t] = sinf(th);
    }
    // --- load state vector psi = x[b] ---
    for (int j = t; j < DIM; j += 256) {
        sre[j] = xr[b * DIM + j];
        sim[j] = xi[b * DIM + j];
    }
    __syncthreads();

    // --- two-qubit layers: q = 0..8, gates RXX,RYY,RZZ,CNOT on (q, q+1) ---
    // qubit q lives at bit position p = 9-q (axis 0 is MSB).
    for (int q = 0; q < NQ - 1; ++q) {
        const int p  = NQ - 1 - q;   // bit of qubit q
        const int pl = p - 1;        // bit of qubit q+1
        const float c1 = sc[3*q],   s1 = ss[3*q];
        const float c2 = sc[3*q+1], s2 = ss[3*q+1];
        const float c3 = sc[3*q+2], s3 = ss[3*q+2];

        // 256 disjoint groups of 4 amplitudes; thread t owns group t.
        const int g    = t;
        const int low  = g & ((1 << pl) - 1);
        const int high = g >> pl;
        const int i0   = (high << (p + 1)) | low;        // basis 00
        const int i1   = i0 | (1 << pl);                  // basis 01
        const int i2   = i0 | (1 << p);                   // basis 10
        const int i3   = i2 | (1 << pl);                  // basis 11

        float r0 = sre[i0], m0 = sim[i0];
        float r1 = sre[i1], m1 = sim[i1];
        float r2 = sre[i2], m2 = sim[i2];
        float r3 = sre[i3], m3 = sim[i3];

        // RXX: new a = c*a - i s * partner, pairs (0,3) and (1,2)
        float t0r = c1*r0 + s1*m3, t0m = c1*m0 - s1*r3;
        float t3r = c1*r3 + s1*m0, t3m = c1*m3 - s1*r0;
        float t1r = c1*r1 + s1*m2, t1m = c1*m1 - s1*r2;
        float t2r = c1*r2 + s1*m1, t2m = c1*m2 - s1*r1;

        // RYY: (0,3): a += +i s * partner ; (1,2): a += -i s * partner
        r0 = c2*t0r - s2*t3m; m0 = c2*t0m + s2*t3r;
        r3 = c2*t3r - s2*t0m; m3 = c2*t3m + s2*t0r;
        r1 = c2*t1r + s2*t2m; m1 = c2*t1m - s2*t2r;
        r2 = c2*t2r + s2*t1m; m2 = c2*t2m - s2*t1r;

        // RZZ: states 00,11 *= (c3 - i s3); states 01,10 *= (c3 + i s3)
        t0r = c3*r0 + s3*m0; t0m = c3*m0 - s3*r0;
        t3r = c3*r3 + s3*m3; t3m = c3*m3 - s3*r3;
        t1r = c3*r1 - s3*m1; t1m = c3*m1 + s3*r1;
        t2r = c3*r2 - s3*m2; t2m = c3*m2 + s3*r2;

        // CNOT (control q, target q+1): swap basis 2 <-> 3 on write-back.
        // Groups are disjoint per thread -> no barrier needed before writes.
        sre[i0] = t0r; sim[i0] = t0m;
        sre[i1] = t1r; sim[i1] = t1m;
        sre[i2] = t3r; sim[i2] = t3m;
        sre[i3] = t2r; sim[i3] = t2m;
        __syncthreads();
    }

    // --- single-qubit layers: q = 0..9, gates RZ,RY,RX on qubit q ---
    for (int q = 0; q < NQ; ++q) {
        const int p = NQ - 1 - q;
        const float cz = sc[27 + 3*q],     szn = ss[27 + 3*q];
        const float cy = sc[27 + 3*q + 1], sy  = ss[27 + 3*q + 1];
        const float cx = sc[27 + 3*q + 2], sx  = ss[27 + 3*q + 2];

        for (int g = t; g < DIM / 2; g += 256) {
            const int low  = g & ((1 << p) - 1);
            const int high = g >> p;
            const int i0   = (high << (p + 1)) | low;
            const int i1   = i0 | (1 << p);

            float ur = sre[i0], ui = sim[i0];
            float vr = sre[i1], vi = sim[i1];

            // RZ: u *= (cz - i sz); v *= (cz + i sz)
            float tur = cz*ur + szn*ui, tui = cz*ui - szn*ur;
            float tvr = cz*vr - szn*vi, tvi = cz*vi + szn*vr;
            // RY: u = cy u - sy v ; v = sy u + cy v
            ur = cy*tur - sy*tvr; ui = cy*tui - sy*tvi;
            vr = sy*tur + cy*tvr; vi = sy*tui + cy*tvi;
            // RX: u = cx u - i sx v ; v = -i sx u + cx v
            tur = cx*ur + sx*vi; tui = cx*ui - sx*vr;
            tvr = cx*vr + sx*ui; tvi = cx*vi - sx*ur;

            sre[i0] = tur; sim[i0] = tui;
            sre[i1] = tvr; sim[i1] = tvi;
        }
        __syncthreads();
    }

    // --- partial trace of rank-1 projector ---
    // red[a,c] = sum_i psi[i*dA + a] * conj(psi[i*dA + c])
    const int dimA = dimA_p[0];
    const int dA   = 1 << dimA;
    const int dB   = DIM >> dimA;
    const int nout = dA * dA;
    const bool cplx = (out_size >= 2 * (int)gridDim.x * nout);

    for (int o = t; o < nout; o += 256) {
        const int a = o / dA;
        const int c = o % dA;
        float accr = 0.f, acci = 0.f;
        for (int i = 0; i < dB; ++i) {
            const int ia = i * dA + a;
            const int ic = i * dA + c;
            const float ar = sre[ia], ai = sim[ia];
            const float cr = sre[ic], ci = sim[ic];
            accr += ar * cr + ai * ci;   // Re(psi_a * conj(psi_c))
            acci += ai * cr - ar * ci;   // Im(psi_a * conj(psi_c))
        }
        const size_t oo = (size_t)b * nout + o;
        if (cplx) {
            out[2 * oo]     = accr;
            out[2 * oo + 1] = acci;
        } else {
            out[oo] = accr;
        }
    }
}

extern "C" void kernel_launch(void* const* d_in, const int* in_sizes, int n_in,
                              void* d_out, int out_size, void* d_ws, size_t ws_size,
                              hipStream_t stream) {
    const float* xr = (const float*)d_in[0];
    const float* xi = (const float*)d_in[1];
    const float* w  = (const float*)d_in[2];
    const int*   dA = (const int*)d_in[3];
    float* out = (float*)d_out;

    const int B = in_sizes[0] / DIM;   // 16
    qupool_sv_kernel<<<dim3(B), dim3(256), 0, stream>>>(xr, xi, w, dA, out, out_size);
}

// Round 2
// 67.232 us; speedup vs baseline: 1.0432x; 1.0432x over previous
//
#include <hip/hip_runtime.h>

#define NQ   10
#define DIM  1024
#define NP   57                       // 6*NQ - 3
#define WMUL 0.6324555320336759f      // sqrt(2/5)

// XOR swizzle: kills the 16-way bank conflicts of the low-bit layers
// (q=6..8 access stride-4 float2 groups -> same bank without this).
__device__ __forceinline__ int ixs(int i) { return i ^ ((i >> 4) & 15); }

// Fused RZ*RY*RX chain on one amplitude pair (u = bit 0, v = bit 1).
// Math identical to the round-1 validated version.
__device__ __forceinline__ void chain1q(float2& u, float2& v,
    float cz, float sz, float cy, float sy, float cx, float sx)
{
    float tur = cz*u.x + sz*u.y, tui = cz*u.y - sz*u.x;   // RZ: u *= (cz - i sz)
    float tvr = cz*v.x - sz*v.y, tvi = cz*v.y + sz*v.x;   //     v *= (cz + i sz)
    float ur = cy*tur - sy*tvr, ui = cy*tui - sy*tvi;     // RY
    float vr = sy*tur + cy*tvr, vi = sy*tui + cy*tvi;
    u.x = cx*ur + sx*vi; u.y = cx*ui - sx*vr;             // RX
    v.x = cx*vr + sx*ui; v.y = cx*vi - sx*ur;
}

// Fused RXX*RYY*RZZ on a 4-amp group (basis order 00,01,10,11 over (p,pl)).
// CNOT is applied by the caller as a write-back swap of A2/A3.
__device__ __forceinline__ void gate2q(float2& A0, float2& A1, float2& A2, float2& A3,
    float c1, float s1, float c2, float s2, float c3, float s3)
{
    // RXX: t_k = c1*a_k - i s1 * a_{k^3}
    float t0r = c1*A0.x + s1*A3.y, t0m = c1*A0.y - s1*A3.x;
    float t3r = c1*A3.x + s1*A0.y, t3m = c1*A3.y - s1*A0.x;
    float t1r = c1*A1.x + s1*A2.y, t1m = c1*A1.y - s1*A2.x;
    float t2r = c1*A2.x + s1*A1.y, t2m = c1*A2.y - s1*A1.x;
    // RYY
    float r0 = c2*t0r - s2*t3m, m0 = c2*t0m + s2*t3r;
    float r3 = c2*t3r - s2*t0m, m3 = c2*t3m + s2*t0r;
    float r1 = c2*t1r + s2*t2m, m1 = c2*t1m - s2*t2r;
    float r2 = c2*t2r + s2*t1m, m2 = c2*t2m - s2*t1r;
    // RZZ
    A0.x = c3*r0 + s3*m0; A0.y = c3*m0 - s3*r0;
    A3.x = c3*r3 + s3*m3; A3.y = c3*m3 - s3*r3;
    A1.x = c3*r1 - s3*m1; A1.y = c3*m1 + s3*r1;
    A2.x = c3*r2 - s3*m2; A2.y = c3*m2 + s3*r2;
}

__global__ __launch_bounds__(256) void qupool_sv_kernel(
    const float* __restrict__ xr,
    const float* __restrict__ xi,
    const float* __restrict__ w,
    const int*   __restrict__ dimA_p,
    float* __restrict__ out,
    int out_size)
{
    __shared__ float2 s[DIM];
    __shared__ float sc[NP], ss[NP];

    const int b = blockIdx.x;
    const int t = threadIdx.x;
    const int base = b * DIM;

    // Layer-0 angles computed redundantly by ALL threads (uniform) -> no
    // barrier needed before the first layer.
    float c1, s1, c2, s2, c3, s3;
    {
        float th0 = w[0] * (WMUL * 0.5f);
        float th1 = w[1] * (WMUL * 0.5f);
        float th2 = w[2] * (WMUL * 0.5f);
        sincosf(th0, &s1, &c1);
        sincosf(th1, &s2, &c2);
        sincosf(th2, &s3, &c3);
    }
    // Full table for the remaining layers.
    if (t < NP) {
        float th = w[t] * (WMUL * 0.5f);
        float sv, cv; sincosf(th, &sv, &cv);
        sc[t] = cv; ss[t] = sv;
    }

    // --- layer q=0 (bits 9,8) fused with the global load ---
    // group t owns amps {t, t+256, t+512, t+768} -> fully coalesced loads.
    {
        float2 A0 = make_float2(xr[base + t      ], xi[base + t      ]);
        float2 A1 = make_float2(xr[base + t + 256], xi[base + t + 256]);
        float2 A2 = make_float2(xr[base + t + 512], xi[base + t + 512]);
        float2 A3 = make_float2(xr[base + t + 768], xi[base + t + 768]);
        gate2q(A0, A1, A2, A3, c1, s1, c2, s2, c3, s3);
        s[ixs(t      )] = A0;
        s[ixs(t + 256)] = A1;
        s[ixs(t + 512)] = A3;   // CNOT swap
        s[ixs(t + 768)] = A2;
    }
    __syncthreads();

    // --- two-qubit layers q = 1..8 ---
    #pragma unroll
    for (int q = 1; q < NQ - 1; ++q) {
        const int p  = NQ - 1 - q;
        const int pl = p - 1;
        const float g1c = sc[3*q  ], g1s = ss[3*q  ];
        const float g2c = sc[3*q+1], g2s = ss[3*q+1];
        const float g3c = sc[3*q+2], g3s = ss[3*q+2];

        const int low  = t & ((1 << pl) - 1);
        const int high = t >> pl;
        const int i0   = (high << (p + 1)) | low;
        const int i1   = i0 | (1 << pl);
        const int i2   = i0 | (1 << p);
        const int i3   = i2 | (1 << pl);

        float2 A0 = s[ixs(i0)], A1 = s[ixs(i1)], A2 = s[ixs(i2)], A3 = s[ixs(i3)];
        gate2q(A0, A1, A2, A3, g1c, g1s, g2c, g2s, g3c, g3s);
        s[ixs(i0)] = A0; s[ixs(i1)] = A1;
        s[ixs(i2)] = A3; s[ixs(i3)] = A2;   // CNOT swap
        __syncthreads();
    }

    // --- single-qubit layers fused in pairs: qubits (2j, 2j+1), bits (9-2j, 8-2j) ---
    // 1q chains on distinct qubits commute -> one LDS round-trip per pair.
    #pragma unroll
    for (int j = 0; j < 5; ++j) {
        const int bl = 8 - 2*j;       // bit of qubit 2j+1
        const int bh = bl + 1;        // bit of qubit 2j
        const int kb = 27 + 6*j;
        const float cz0 = sc[kb+0], sz0 = ss[kb+0];
        const float cy0 = sc[kb+1], sy0 = ss[kb+1];
        const float cx0 = sc[kb+2], sx0 = ss[kb+2];
        const float cz1 = sc[kb+3], sz1 = ss[kb+3];
        const float cy1 = sc[kb+4], sy1 = ss[kb+4];
        const float cx1 = sc[kb+5], sx1 = ss[kb+5];

        const int low  = t & ((1 << bl) - 1);
        const int high = t >> bl;
        const int i0   = (high << (bh + 1)) | low;
        const int i1   = i0 | (1 << bl);
        const int i2   = i0 | (1 << bh);
        const int i3   = i2 | (1 << bl);

        float2 A0 = s[ixs(i0)], A1 = s[ixs(i1)], A2 = s[ixs(i2)], A3 = s[ixs(i3)];
        // qubit 2j on bit bh: pairs (A0,A2),(A1,A3)
        chain1q(A0, A2, cz0, sz0, cy0, sy0, cx0, sx0);
        chain1q(A1, A3, cz0, sz0, cy0, sy0, cx0, sx0);
        // qubit 2j+1 on bit bl: pairs (A0,A1),(A2,A3)
        chain1q(A0, A1, cz1, sz1, cy1, sy1, cx1, sx1);
        chain1q(A2, A3, cz1, sz1, cy1, sy1, cx1, sx1);
        s[ixs(i0)] = A0; s[ixs(i1)] = A1; s[ixs(i2)] = A2; s[ixs(i3)] = A3;
        __syncthreads();
    }

    // --- partial trace of rank-1 projector: red[a,c] = sum_i psi[i*dA+a] conj(psi[i*dA+c]) ---
    const int dimA = dimA_p[0];
    const int dA   = 1 << dimA;
    const int nout = dA * dA;
    const bool cplx = (out_size >= 2 * (int)gridDim.x * nout);

    if (dA == 32) {
        // outputs o = t + 256k -> a = (t>>5)+8k, c = t&31 (constant per thread)
        const int c  = t & 31;
        const int a0 = t >> 5;
        float ar[4]  = {0.f, 0.f, 0.f, 0.f};
        float aim[4] = {0.f, 0.f, 0.f, 0.f};
        #pragma unroll 4
        for (int iB = 0; iB < 32; ++iB) {
            const float2 vc = s[ixs(iB*32 + c)];
            #pragma unroll
            for (int k = 0; k < 4; ++k) {
                const float2 va = s[ixs(iB*32 + a0 + 8*k)];
                ar[k]  += va.x*vc.x + va.y*vc.y;
                aim[k] += va.y*vc.x - va.x*vc.y;
            }
        }
        #pragma unroll
        for (int k = 0; k < 4; ++k) {
            const size_t oo = (size_t)b*nout + (t + 256*k);
            if (cplx) { out[2*oo] = ar[k]; out[2*oo+1] = aim[k]; }
            else      { out[oo] = ar[k]; }
        }
    } else {
        const int dB = DIM >> dimA;
        for (int o = t; o < nout; o += 256) {
            const int a = o >> dimA;
            const int c = o & (dA - 1);
            float accr = 0.f, acci = 0.f;
            for (int i = 0; i < dB; ++i) {
                const float2 va = s[ixs(i*dA + a)];
                const float2 vv = s[ixs(i*dA + c)];
                accr += va.x*vv.x + va.y*vv.y;
                acci += va.y*vv.x - va.x*vv.y;
            }
            const size_t oo = (size_t)b*nout + o;
            if (cplx) { out[2*oo] = accr; out[2*oo+1] = acci; }
            else      { out[oo] = accr; }
        }
    }
}

extern "C" void kernel_launch(void* const* d_in, const int* in_sizes, int n_in,
                              void* d_out, int out_size, void* d_ws, size_t ws_size,
                              hipStream_t stream) {
    const float* xr = (const float*)d_in[0];
    const float* xi = (const float*)d_in[1];
    const float* w  = (const float*)d_in[2];
    const int*   dA = (const int*)d_in[3];
    float* out = (float*)d_out;

    const int B = in_sizes[0] / DIM;   // 16
    qupool_sv_kernel<<<dim3(B), dim3(256), 0, stream>>>(xr, xi, w, dA, out, out_size);
}

// Round 3
// 66.472 us; speedup vs baseline: 1.0551x; 1.0114x over previous
//
#include <hip/hip_runtime.h>

#define NQ   10
#define DIM  1024
#define NP   57                       // 6*NQ - 3
#define WMUL 0.6324555320336759f      // sqrt(2/5)

// XOR swizzle for LDS bank spread (validated rounds 1-2).
__device__ __forceinline__ int ixs(int i) { return i ^ ((i >> 4) & 15); }

__device__ __forceinline__ float2 shflx2(float2 v, int m) {
    float2 r;
    r.x = __shfl_xor(v.x, m);
    r.y = __shfl_xor(v.y, m);
    return r;
}

// Fused RZ*RY*RX chain on one amplitude pair (u = qubit bit 0, v = bit 1).
__device__ __forceinline__ void chain1q(float2& u, float2& v,
    float cz, float sz, float cy, float sy, float cx, float sx)
{
    float tur = cz*u.x + sz*u.y, tui = cz*u.y - sz*u.x;   // RZ
    float tvr = cz*v.x - sz*v.y, tvi = cz*v.y + sz*v.x;
    float ur = cy*tur - sy*tvr, ui = cy*tui - sy*tvi;     // RY
    float vr = sy*tur + cy*tvr, vi = sy*tui + cy*tvi;
    u.x = cx*ur + sx*vi; u.y = cx*ui - sx*vr;             // RX
    v.x = cx*vr + sx*ui; v.y = cx*vi - sx*ur;
}

// Fused RXX*RYY*RZZ on a 4-amp group (basis 00,01,10,11 over (p,pl)).
// CNOT applied by caller as an output relabel.
__device__ __forceinline__ void gate2q(float2& A0, float2& A1, float2& A2, float2& A3,
    float c1, float s1, float c2, float s2, float c3, float s3)
{
    float t0r = c1*A0.x + s1*A3.y, t0m = c1*A0.y - s1*A3.x;
    float t3r = c1*A3.x + s1*A0.y, t3m = c1*A3.y - s1*A0.x;
    float t1r = c1*A1.x + s1*A2.y, t1m = c1*A1.y - s1*A2.x;
    float t2r = c1*A2.x + s1*A1.y, t2m = c1*A2.y - s1*A1.x;
    float r0 = c2*t0r - s2*t3m, m0 = c2*t0m + s2*t3r;
    float r3 = c2*t3r - s2*t0m, m3 = c2*t3m + s2*t0r;
    float r1 = c2*t1r + s2*t2m, m1 = c2*t1m - s2*t2r;
    float r2 = c2*t2r + s2*t1m, m2 = c2*t2m - s2*t1r;
    A0.x = c3*r0 + s3*m0; A0.y = c3*m0 - s3*r0;
    A3.x = c3*r3 + s3*m3; A3.y = c3*m3 - s3*r3;
    A1.x = c3*r1 - s3*m1; A1.y = c3*m1 + s3*r1;
    A2.x = c3*r2 - s3*m2; A2.y = c3*m2 + s3*r2;
}

// One fused round: 2q layer QA=9-B2 on bits (B2,B2-1), then layer QA+1 on
// (B2-1,B2-2). Thread t: b0 = t&1, 7 free bits = t>>1. Exchange with lane t^1
// repartitions the 8-amp cube from "b0 fixed" to "b2 fixed". For B2==2 the
// 1q chains on qubits 8,9 (bits 1,0) are fused in before the write.
template<int B2>
__device__ __forceinline__ void fused2q_round(float2* __restrict__ s, int t,
                                              const float* __restrict__ sc,
                                              const float* __restrict__ ss)
{
    constexpr int B1 = B2 - 1, B0 = B2 - 2;
    constexpr int QA = 9 - B2;
    const float a1c = sc[3*QA+0], a1s = ss[3*QA+0];
    const float a2c = sc[3*QA+1], a2s = ss[3*QA+1];
    const float a3c = sc[3*QA+2], a3s = ss[3*QA+2];
    const float b1c = sc[3*QA+3], b1s = ss[3*QA+3];
    const float b2c = sc[3*QA+4], b2s = ss[3*QA+4];
    const float b3c = sc[3*QA+5], b3s = ss[3*QA+5];

    const int my   = t & 1;
    const int u    = t >> 1;
    const int low  = u & ((1 << B0) - 1);
    const int high = u >> B0;
    const int rb   = (high << (B2 + 1)) | low | (my << B0);

    float2 A0 = s[ixs(rb)];
    float2 A1 = s[ixs(rb | (1 << B1))];
    float2 A2 = s[ixs(rb | (1 << B2))];
    float2 A3 = s[ixs(rb | (1 << B2) | (1 << B1))];
    gate2q(A0, A1, A2, A3, a1c, a1s, a2c, a2s, a3c, a3s);
    // post-CNOT relabel: B[b2][b1] = {A0, A1, A3, A2}
    float2 B00 = A0, B01 = A1, B10 = A3, B11 = A2;

    // pass B[1-my][b1]; partner's same expression is exactly what we need.
    float2 snd0 = my ? B00 : B10;
    float2 snd1 = my ? B01 : B11;
    float2 rcv0 = shflx2(snd0, 1);
    float2 rcv1 = shflx2(snd1, 1);
    float2 kp0  = my ? B10 : B00;          // B[my][0]
    float2 kp1  = my ? B11 : B01;          // B[my][1]

    // D[b1][b0] with b2 = my:  D[b1][my] = kept, D[b1][1-my] = received
    float2 D00 = my ? rcv0 : kp0;
    float2 D01 = my ? kp0  : rcv0;
    float2 D10 = my ? rcv1 : kp1;
    float2 D11 = my ? kp1  : rcv1;
    gate2q(D00, D01, D10, D11, b1c, b1s, b2c, b2s, b3c, b3s);
    // post-CNOT: E[b1][b0] = {D00, D01, D11, D10}
    float2 E00 = D00, E01 = D01, E10 = D11, E11 = D10;

    if (B2 == 2) {
        // qubit 8 on bit 1, qubit 9 on bit 0 — both local now.
        chain1q(E00, E10, sc[51], ss[51], sc[52], ss[52], sc[53], ss[53]);
        chain1q(E01, E11, sc[51], ss[51], sc[52], ss[52], sc[53], ss[53]);
        chain1q(E00, E01, sc[54], ss[54], sc[55], ss[55], sc[56], ss[56]);
        chain1q(E10, E11, sc[54], ss[54], sc[55], ss[55], sc[56], ss[56]);
    }

    const int wb = (high << (B2 + 1)) | low | (my << B2);
    s[ixs(wb)]                         = E00;
    s[ixs(wb | (1 << B0))]             = E01;
    s[ixs(wb | (1 << B1))]             = E10;
    s[ixs(wb | (1 << B1) | (1 << B0))] = E11;
}

// 4-qubit 1q round over a 4-lane cluster. Cluster bits (c1,c0) = amp bits
// (CB, CB-1) hold qubits QH0,QH1; register slots (r1,r0) = amp bits
// (RB, RB-1) hold qubits QL0,QL1. Apply QL locally, fswap regs<->cluster
// bits via shfl_xor(2)/(1), apply QH locally. Writes with bits exchanged.
template<int CB, int RB, int QH0, int QH1, int QL0, int QL1>
__device__ __forceinline__ void cluster1q_round(float2* __restrict__ s, int t,
                                                const float* __restrict__ sc,
                                                const float* __restrict__ ss)
{
    const int c1 = (t >> 1) & 1, c0 = t & 1;
    const int u  = t >> 2;                       // 6 free bits
    const int low  = u & ((1 << (RB - 1)) - 1);
    const int high = u >> (RB - 1);
    const int ib = (high << (CB + 1)) | (c1 << CB) | (c0 << (CB - 1)) | low;

    float2 F00 = s[ixs(ib)];
    float2 F01 = s[ixs(ib | (1 << (RB - 1)))];
    float2 F10 = s[ixs(ib | (1 << RB))];
    float2 F11 = s[ixs(ib | (1 << RB) | (1 << (RB - 1)))];

    // QL0 on slot r1, QL1 on slot r0 (local)
    chain1q(F00, F10, sc[27+3*QL0], ss[27+3*QL0], sc[28+3*QL0], ss[28+3*QL0], sc[29+3*QL0], ss[29+3*QL0]);
    chain1q(F01, F11, sc[27+3*QL0], ss[27+3*QL0], sc[28+3*QL0], ss[28+3*QL0], sc[29+3*QL0], ss[29+3*QL0]);
    chain1q(F00, F01, sc[27+3*QL1], ss[27+3*QL1], sc[28+3*QL1], ss[28+3*QL1], sc[29+3*QL1], ss[29+3*QL1]);
    chain1q(F10, F11, sc[27+3*QL1], ss[27+3*QL1], sc[28+3*QL1], ss[28+3*QL1], sc[29+3*QL1], ss[29+3*QL1]);

    // fswap cluster bit c1 <-> slot r1 (partner t^2): pass slot[1-c1], recv -> slot[1-c1]
    {
        float2 s0 = c1 ? F00 : F10;
        float2 s1 = c1 ? F01 : F11;
        float2 g0 = shflx2(s0, 2), g1 = shflx2(s1, 2);
        if (c1) { F00 = g0; F01 = g1; } else { F10 = g0; F11 = g1; }
    }
    // fswap cluster bit c0 <-> slot r0 (partner t^1)
    {
        float2 s0 = c0 ? F00 : F01;
        float2 s1 = c0 ? F10 : F11;
        float2 g0 = shflx2(s0, 1), g1 = shflx2(s1, 1);
        if (c0) { F00 = g0; F10 = g1; } else { F01 = g0; F11 = g1; }
    }

    // QH0 now on slot r1, QH1 on slot r0
    chain1q(F00, F10, sc[27+3*QH0], ss[27+3*QH0], sc[28+3*QH0], ss[28+3*QH0], sc[29+3*QH0], ss[29+3*QH0]);
    chain1q(F01, F11, sc[27+3*QH0], ss[27+3*QH0], sc[28+3*QH0], ss[28+3*QH0], sc[29+3*QH0], ss[29+3*QH0]);
    chain1q(F00, F01, sc[27+3*QH1], ss[27+3*QH1], sc[28+3*QH1], ss[28+3*QH1], sc[29+3*QH1], ss[29+3*QH1]);
    chain1q(F10, F11, sc[27+3*QH1], ss[27+3*QH1], sc[28+3*QH1], ss[28+3*QH1], sc[29+3*QH1], ss[29+3*QH1]);

    // write: slots -> bits (CB, CB-1); cluster bits -> (RB, RB-1)
    const int jb = (high << (CB + 1)) | (c1 << RB) | (c0 << (RB - 1)) | low;
    s[ixs(jb)]                              = F00;
    s[ixs(jb | (1 << (CB - 1)))]            = F01;
    s[ixs(jb | (1 << CB))]                  = F10;
    s[ixs(jb | (1 << CB) | (1 << (CB-1)))]  = F11;
}

__global__ __launch_bounds__(256) void qupool_sv_kernel(
    const float* __restrict__ xr,
    const float* __restrict__ xi,
    const float* __restrict__ w,
    const int*   __restrict__ dimA_p,
    float* __restrict__ out,
    int out_size)
{
    __shared__ float2 s[DIM];
    __shared__ float sc[NP], ss[NP];

    const int b = blockIdx.x;
    const int t = threadIdx.x;
    const int base = b * DIM;

    // issue global loads first
    float2 A0 = make_float2(xr[base + t      ], xi[base + t      ]);
    float2 A1 = make_float2(xr[base + t + 256], xi[base + t + 256]);
    float2 A2 = make_float2(xr[base + t + 512], xi[base + t + 512]);
    float2 A3 = make_float2(xr[base + t + 768], xi[base + t + 768]);

    // layer-0 angles: computed redundantly by all threads (no barrier needed)
    float c1, s1, c2, s2, c3, s3;
    {
        float sv, cv;
        sincosf(w[0] * (WMUL * 0.5f), &sv, &cv); c1 = cv; s1 = sv;
        sincosf(w[1] * (WMUL * 0.5f), &sv, &cv); c2 = cv; s2 = sv;
        sincosf(w[2] * (WMUL * 0.5f), &sv, &cv); c3 = cv; s3 = sv;
    }
    if (t < NP) {
        float sv, cv; sincosf(w[t] * (WMUL * 0.5f), &sv, &cv);
        sc[t] = cv; ss[t] = sv;
    }

    // --- R0: layer 0 (bits 9,8) fused with the load ---
    gate2q(A0, A1, A2, A3, c1, s1, c2, s2, c3, s3);
    s[ixs(t      )] = A0;
    s[ixs(t + 256)] = A1;
    s[ixs(t + 512)] = A3;   // CNOT swap
    s[ixs(t + 768)] = A2;
    __syncthreads();

    // --- R1-R4: fused 2q layer pairs ---
    fused2q_round<8>(s, t, sc, ss);  __syncthreads();   // layers 1,2
    fused2q_round<6>(s, t, sc, ss);  __syncthreads();   // layers 3,4
    fused2q_round<4>(s, t, sc, ss);  __syncthreads();   // layers 5,6
    fused2q_round<2>(s, t, sc, ss);  __syncthreads();   // layers 7,8 + 1q q8,q9

    // --- R5-R6: 1q on qubits 0-3 then 4-7 ---
    cluster1q_round<9, 7, 0, 1, 2, 3>(s, t, sc, ss); __syncthreads();
    cluster1q_round<5, 3, 4, 5, 6, 7>(s, t, sc, ss); __syncthreads();

    // --- R7: partial trace of rank-1 projector ---
    const int dimA = dimA_p[0];
    const int dA   = 1 << dimA;
    const int nout = dA * dA;
    const bool cplx = (out_size >= 2 * (int)gridDim.x * nout);

    if (dA == 32) {
        const int c  = t & 31;
        const int a0 = t >> 5;
        float ar[4]  = {0.f, 0.f, 0.f, 0.f};
        float aim[4] = {0.f, 0.f, 0.f, 0.f};
        #pragma unroll 4
        for (int iB = 0; iB < 32; ++iB) {
            const float2 vc = s[ixs(iB*32 + c)];
            #pragma unroll
            for (int k = 0; k < 4; ++k) {
                const float2 va = s[ixs(iB*32 + a0 + 8*k)];
                ar[k]  += va.x*vc.x + va.y*vc.y;
                aim[k] += va.y*vc.x - va.x*vc.y;
            }
        }
        #pragma unroll
        for (int k = 0; k < 4; ++k) {
            const size_t oo = (size_t)b*nout + (t + 256*k);
            if (cplx) { out[2*oo] = ar[k]; out[2*oo+1] = aim[k]; }
            else      { out[oo] = ar[k]; }
        }
    } else {
        const int dB = DIM >> dimA;
        for (int o = t; o < nout; o += 256) {
            const int a = o >> dimA;
            const int c = o & (dA - 1);
            float accr = 0.f, acci = 0.f;
            for (int i = 0; i < dB; ++i) {
                const float2 va = s[ixs(i*dA + a)];
                const float2 vv = s[ixs(i*dA + c)];
                accr += va.x*vv.x + va.y*vv.y;
                acci += va.y*vv.x - va.x*vv.y;
            }
            const size_t oo = (size_t)b*nout + o;
            if (cplx) { out[2*oo] = accr; out[2*oo+1] = acci; }
            else      { out[oo] = accr; }
        }
    }
}

extern "C" void kernel_launch(void* const* d_in, const int* in_sizes, int n_in,
                              void* d_out, int out_size, void* d_ws, size_t ws_size,
                              hipStream_t stream) {
    const float* xr = (const float*)d_in[0];
    const float* xi = (const float*)d_in[1];
    const float* w  = (const float*)d_in[2];
    const int*   dA = (const int*)d_in[3];
    float* out = (float*)d_out;

    const int B = in_sizes[0] / DIM;   // 16
    qupool_sv_kernel<<<dim3(B), dim3(256), 0, stream>>>(xr, xi, w, dA, out, out_size);
}